// Round 7
// baseline (904.592 us; speedup 1.0000x reference)
//
#include <hip/hip_runtime.h>
#include <math.h>

#define LN_EPS 1e-5f

typedef _Float16 h8 __attribute__((ext_vector_type(8)));
typedef _Float16 h4 __attribute__((ext_vector_type(4)));
typedef float f32x4 __attribute__((ext_vector_type(4)));

#define MFMA16(A,B,C) __builtin_amdgcn_mfma_f32_16x16x32_f16(A,B,C,0,0,0)

__device__ __forceinline__ float fast_tanh(float x){
    float e = __expf(2.f*x);
    return 1.f - 2.f/(e+1.f);
}

// ---------------------------------------------------------------------------
// dp_kernel: dp[m][k] = LN_k(tanh(V@Hd^T))*g_d+b_d, fp16, fragment-packed:
//   slot[mt][kk][lane][j] = dp[16*mt + (lane&15)][32*kk + 8*(lane>>4) + j]
// ---------------------------------------------------------------------------
__global__ __launch_bounds__(512) void dp_kernel(
    const float* __restrict__ V, const float* __restrict__ Hd,
    const float* __restrict__ gd, const float* __restrict__ bd,
    _Float16* __restrict__ dp_pack)
{
    __shared__ float h_sh[4][256];
    __shared__ float red1[4][8];
    __shared__ float red2[4][8];

    const int t  = threadIdx.x;
    const int m0 = blockIdx.x * 4;

    for (int i = t; i < 4 * 256; i += 512)
        ((float*)h_sh)[i] = Hd[(size_t)m0 * 256 + i];
    __syncthreads();

    const int k = t;
    float x0 = 0.f, x1 = 0.f, x2 = 0.f, x3 = 0.f;
    for (int j = 0; j < 256; j += 4) {
        float4 v4 = *(const float4*)(V + (size_t)k * 256 + j);
        x0 += v4.x * h_sh[0][j] + v4.y * h_sh[0][j + 1] + v4.z * h_sh[0][j + 2] + v4.w * h_sh[0][j + 3];
        x1 += v4.x * h_sh[1][j] + v4.y * h_sh[1][j + 1] + v4.z * h_sh[1][j + 2] + v4.w * h_sh[1][j + 3];
        x2 += v4.x * h_sh[2][j] + v4.y * h_sh[2][j + 1] + v4.z * h_sh[2][j + 2] + v4.w * h_sh[2][j + 3];
        x3 += v4.x * h_sh[3][j] + v4.y * h_sh[3][j + 1] + v4.z * h_sh[3][j + 2] + v4.w * h_sh[3][j + 3];
    }
    float th[4];
    th[0] = tanhf(x0); th[1] = tanhf(x1); th[2] = tanhf(x2); th[3] = tanhf(x3);

    float s1[4], s2[4];
#pragma unroll
    for (int mi = 0; mi < 4; ++mi) { s1[mi] = th[mi]; s2[mi] = th[mi] * th[mi]; }
#pragma unroll
    for (int off = 32; off > 0; off >>= 1) {
#pragma unroll
        for (int mi = 0; mi < 4; ++mi) {
            s1[mi] += __shfl_xor(s1[mi], off, 64);
            s2[mi] += __shfl_xor(s2[mi], off, 64);
        }
    }
    const int wave = t >> 6;
    if ((t & 63) == 0) {
#pragma unroll
        for (int mi = 0; mi < 4; ++mi) { red1[mi][wave] = s1[mi]; red2[mi][wave] = s2[mi]; }
    }
    __syncthreads();

    const float gk = gd[k];
    const float bk = bd[k];
#pragma unroll
    for (int mi = 0; mi < 4; ++mi) {
        float sa = 0.f, sb = 0.f;
#pragma unroll
        for (int ww = 0; ww < 8; ++ww) { sa += red1[mi][ww]; sb += red2[mi][ww]; }
        float mu  = sa * (1.f / 512.f);
        float var = sb * (1.f / 512.f) - mu * mu;
        float rs  = rsqrtf(var + LN_EPS);
        float a   = (th[mi] - mu) * rs * gk + bk;
        int m  = m0 + mi;
        int mt = m >> 4, kk = k >> 5, ln = (m & 15) + 16 * ((k >> 3) & 3), j = k & 7;
        dp_pack[(size_t)((mt * 16 + kk) * 64 + ln) * 8 + j] = (_Float16)a;
    }
}

// hd_pack[nt][kk][lane][j] = Hd[32*kk + 8*(lane>>4)+j][16*nt + (lane&15)]  (fp16)
__global__ void pack_hd_kernel(const float* __restrict__ Hd, _Float16* __restrict__ hp)
{
    int m = blockIdx.x, c = threadIdx.x;
    float v = Hd[(size_t)m * 256 + c];
    int nt = c >> 4, kk = m >> 5, ln = (c & 15) + 16 * ((m >> 3) & 3), j = m & 7;
    hp[(size_t)((nt * 64 + kk) * 64 + ln) * 8 + j] = (_Float16)v;
}

// u_pack[nt][kd][lane][jj] = U[32*kd + 8*(lane>>4)+jj][16*nt + (lane&15)]  hi/lo fp16
__global__ void pack_u_kernel(const float* __restrict__ U,
                              _Float16* __restrict__ uh, _Float16* __restrict__ ul)
{
    int jd = blockIdx.x, n = threadIdx.x;
    float v = U[(size_t)jd * 512 + n];
    _Float16 hi = (_Float16)v;
    _Float16 lo = (_Float16)(v - (float)hi);
    int nt = n >> 4, kd = jd >> 5, ln = (n & 15) + 16 * ((jd >> 3) & 3), jj = jd & 7;
    int idx = ((nt * 8 + kd) * 64 + ln) * 8 + jj;
    uh[idx] = hi; ul[idx] = lo;
}

// ---------------------------------------------------------------------------
// Main kernel: 128 rows/block, 512 threads (8 waves), WAVE-DECOUPLED M-loop.
// KEY FIX vs round 6: __launch_bounds__(512, 1). Empirical mapping on this
// toolchain: VGPR cap = 256/arg2 regardless of block size ((256,1)->256,
// (256,3)->84, (512)->128, (512,2)->128). The M-loop holds ~200 live regs
// (a[16]=64 + o[16]=64 + s/staging/softmax); arg2=1 unlocks the 256 cap so
// the loop finally runs UNSPILLED. Actual occupancy is unchanged: LDS 148KB
// already pins 1 block/CU = 2 waves/SIMD, and 2 x 256 VGPR fills the file.
// ---------------------------------------------------------------------------
__global__ __launch_bounds__(512, 1) void attn_kernel(
    const float* __restrict__ Hr, const float* __restrict__ q,
    const float* __restrict__ gr, const float* __restrict__ br,
    const _Float16* __restrict__ u_hi, const _Float16* __restrict__ u_lo,
    const _Float16* __restrict__ dp_pack, const _Float16* __restrict__ hd_pack,
    float* __restrict__ out)
{
    __shared__ __align__(16) _Float16 lds0[65536];   // 128 KB: hr staging / a_pack
    __shared__ __align__(16) _Float16 p_lds[8192];   // 16 KB: per-wave P transpose
    __shared__ __align__(16) float stats[2][64][8];  // 4 KB: phase-A LN stats

    const int t    = threadIdx.x;
    const int w    = t >> 6;       // 0..7
    const int lane = t & 63;
    const int q4   = lane >> 4;
    const int l15  = lane & 15;
    const int blk  = blockIdx.x;

    _Float16* hr_hi  = lds0 + 32768;   // bytes [64K,96K)
    _Float16* hr_lo  = lds0 + 49152;   // bytes [96K,128K)
    _Float16* a_pack = lds0;           // rt'=0..7 -> [0,128K)

    // per-thread LN gate params for this wave's 64 K-cols
    float gq[4], bq[4];
#pragma unroll
    for (int i = 0; i < 4; ++i) {
        int c = w * 64 + 16 * i + l15;
        gq[i] = gr[c] * q[c];
        bq[i] = br[c] * q[c];
    }

    // ======================= phase A: two 64-row passes =======================
    for (int pass = 0; pass < 2; ++pass) {
        // stage 64 rows of Hr -> hi/lo A-fragments (coalesced, NT loads)
        const float* HrB = Hr + ((size_t)blk * 128 + pass * 64) * 256;
#pragma unroll
        for (int ii = 0; ii < 8; ++ii) {
            int flat = (t + 512 * ii) * 4;
            int r = flat >> 8, c = flat & 255;
            f32x4 v = __builtin_nontemporal_load((const f32x4*)(HrB + flat));
            int base = (((r >> 4) * 8 + (c >> 5)) * 64 + ((r & 15) + 16 * ((c >> 3) & 3))) * 8 + (c & 7);
            h4 hi, lo;
            hi[0] = (_Float16)v[0]; lo[0] = (_Float16)(v[0] - (float)hi[0]);
            hi[1] = (_Float16)v[1]; lo[1] = (_Float16)(v[1] - (float)hi[1]);
            hi[2] = (_Float16)v[2]; lo[2] = (_Float16)(v[2] - (float)hi[2]);
            hi[3] = (_Float16)v[3]; lo[3] = (_Float16)(v[3] - (float)hi[3]);
            *(h4*)(hr_hi + base) = hi;
            *(h4*)(hr_lo + base) = lo;
        }
        __syncthreads();   // staging complete

        // x[rt][ci] = Hr@U (split fp16 3-product); wave owns K-cols [w*64, +64)
        f32x4 x[4][4];
#pragma unroll
        for (int rt = 0; rt < 4; ++rt)
#pragma unroll
            for (int ci = 0; ci < 4; ++ci) x[rt][ci] = (f32x4)(0.f);

#pragma unroll
        for (int kd = 0; kd < 8; ++kd) {
            h8 ah[4], al[4];
#pragma unroll
            for (int rt = 0; rt < 4; ++rt) {
                int idx = ((rt * 8 + kd) * 64 + lane) * 8;
                ah[rt] = *(h8*)(hr_hi + idx);
                al[rt] = *(h8*)(hr_lo + idx);
            }
            h8 bh[4], bl[4];
#pragma unroll
            for (int ci = 0; ci < 4; ++ci) {
                int idx = (((w * 4 + ci) * 8 + kd) * 64 + lane) * 8;
                bh[ci] = *(const h8*)(u_hi + idx);
                bl[ci] = *(const h8*)(u_lo + idx);
            }
            __builtin_amdgcn_s_setprio(1);
#pragma unroll
            for (int rt = 0; rt < 4; ++rt)
#pragma unroll
                for (int ci = 0; ci < 4; ++ci) x[rt][ci] = MFMA16(ah[rt], bh[ci], x[rt][ci]);
#pragma unroll
            for (int rt = 0; rt < 4; ++rt)
#pragma unroll
                for (int ci = 0; ci < 4; ++ci) x[rt][ci] = MFMA16(ah[rt], bl[ci], x[rt][ci]);
#pragma unroll
            for (int rt = 0; rt < 4; ++rt)
#pragma unroll
                for (int ci = 0; ci < 4; ++ci) x[rt][ci] = MFMA16(al[rt], bh[ci], x[rt][ci]);
            __builtin_amdgcn_s_setprio(0);
        }

        // tanh + LN stats (8-wave reduction through LDS)
        float s1[4][4], s2[4][4];
#pragma unroll
        for (int rt = 0; rt < 4; ++rt)
#pragma unroll
            for (int e = 0; e < 4; ++e) { s1[rt][e] = 0.f; s2[rt][e] = 0.f; }
#pragma unroll
        for (int rt = 0; rt < 4; ++rt)
#pragma unroll
            for (int ci = 0; ci < 4; ++ci)
#pragma unroll
                for (int e = 0; e < 4; ++e) {
                    float th = fast_tanh(x[rt][ci][e]);
                    x[rt][ci][e] = th;
                    s1[rt][e] += th;
                    s2[rt][e] += th * th;
                }
#pragma unroll
        for (int off = 1; off < 16; off <<= 1)
#pragma unroll
            for (int rt = 0; rt < 4; ++rt)
#pragma unroll
                for (int e = 0; e < 4; ++e) {
                    s1[rt][e] += __shfl_xor(s1[rt][e], off, 64);
                    s2[rt][e] += __shfl_xor(s2[rt][e], off, 64);
                }
        if (l15 == 0) {
#pragma unroll
            for (int rt = 0; rt < 4; ++rt)
#pragma unroll
                for (int e = 0; e < 4; ++e) {
                    int row = rt * 16 + q4 * 4 + e;
                    stats[0][row][w] = s1[rt][e];
                    stats[1][row][w] = s2[rt][e];
                }
        }
        __syncthreads();   // stats visible (also fences hr reads before reuse)

        float mu[4][4], rs_[4][4];
#pragma unroll
        for (int rt = 0; rt < 4; ++rt)
#pragma unroll
            for (int e = 0; e < 4; ++e) {
                int row = rt * 16 + q4 * 4 + e;
                f32x4 v1  = *(f32x4*)&stats[0][row][0];
                f32x4 v1b = *(f32x4*)&stats[0][row][4];
                f32x4 v2  = *(f32x4*)&stats[1][row][0];
                f32x4 v2b = *(f32x4*)&stats[1][row][4];
                float S1 = v1[0]+v1[1]+v1[2]+v1[3]+v1b[0]+v1b[1]+v1b[2]+v1b[3];
                float S2 = v2[0]+v2[1]+v2[2]+v2[3]+v2b[0]+v2b[1]+v2b[2]+v2b[3];
                float m  = S1 * (1.f / 512.f);
                float va = S2 * (1.f / 512.f) - m * m;
                mu[rt][e]  = m;
                rs_[rt][e] = rsqrtf(va + LN_EPS);
            }

        // LN affine + gate -> a_pack (pass 0 -> [0,64K) bytes; pass 1 overwrites hr)
#pragma unroll
        for (int rt = 0; rt < 4; ++rt)
#pragma unroll
            for (int ci = 0; ci < 4; ++ci)
#pragma unroll
                for (int e = 0; e < 4; ++e) {
                    int mrow = q4 * 4 + e;
                    int c = w * 64 + 16 * ci + l15;
                    float a = (x[rt][ci][e] - mu[rt][e]) * rs_[rt][e] * gq[ci] + bq[ci];
                    a_pack[(((pass * 4 + rt) * 16 + (c >> 5)) * 64 + (mrow + 16 * ((c >> 3) & 3))) * 8 + (c & 7)] =
                        (_Float16)a;
                }
    }
    __syncthreads();   // a_pack complete (written by all waves)

    // ======================= wave-decoupled flash M-loop ======================
    // a row-tile (16 rows x 512 K) into registers: 16 x h8 = 64 VGPR
    h8 a[16];
#pragma unroll
    for (int kk = 0; kk < 16; ++kk)
        a[kk] = *(h8*)(a_pack + ((w * 16 + kk) * 64 + lane) * 8);

    _Float16* pw = p_lds + w * 1024;   // wave-private 2 KB transpose buffer

    f32x4 o[16];
#pragma unroll
    for (int ct = 0; ct < 16; ++ct) o[ct] = (f32x4)(0.f);
    float m_[4], l_[4];
#pragma unroll
    for (int e = 0; e < 4; ++e) { m_[e] = -3.0e38f; l_[e] = 0.f; }

    for (int itc = 0; itc < 32; ++itc) {   // chunk = 64 M-cols
        // ---- S = a @ dp^T (plain loads; 256-VGPR budget lets compiler hoist) ----
        f32x4 s[4];
#pragma unroll
        for (int ct2 = 0; ct2 < 4; ++ct2) s[ct2] = (f32x4)(0.f);

#pragma unroll
        for (int kk = 0; kk < 16; ++kk) {
            h8 bf[4];
#pragma unroll
            for (int ct2 = 0; ct2 < 4; ++ct2)
                bf[ct2] = *(const h8*)(dp_pack + (size_t)(((itc * 4 + ct2) * 16 + kk) * 64 + lane) * 8);
            __builtin_amdgcn_s_setprio(1);
#pragma unroll
            for (int ct2 = 0; ct2 < 4; ++ct2)
                s[ct2] = MFMA16(a[kk], bf[ct2], s[ct2]);
            __builtin_amdgcn_s_setprio(0);
        }

        // ---- wave-local online softmax over this chunk ----
        float pm[4];
#pragma unroll
        for (int e = 0; e < 4; ++e)
            pm[e] = fmaxf(fmaxf(s[0][e], s[1][e]), fmaxf(s[2][e], s[3][e]));
#pragma unroll
        for (int off = 1; off < 16; off <<= 1)
#pragma unroll
            for (int e = 0; e < 4; ++e)
                pm[e] = fmaxf(pm[e], __shfl_xor(pm[e], off, 64));

        float grow = fmaxf(fmaxf(pm[0] - m_[0], pm[1] - m_[1]),
                           fmaxf(pm[2] - m_[2], pm[3] - m_[3]));
        if (__any(grow > 8.f)) {   // T13 defer-max: rescale only on real growth
#pragma unroll
            for (int e = 0; e < 4; ++e) {
                float mn = fmaxf(m_[e], pm[e]);
                float al = __expf(m_[e] - mn);
                m_[e] = mn;
                l_[e] *= al;
#pragma unroll
                for (int ct = 0; ct < 16; ++ct) o[ct][e] *= al;
            }
        }
        // P = exp(S - m); l as per-thread partial (no cross-lane reduce here)
#pragma unroll
        for (int ct2 = 0; ct2 < 4; ++ct2)
#pragma unroll
            for (int e = 0; e < 4; ++e) {
                float p = __expf(s[ct2][e] - m_[e]);
                s[ct2][e] = p;
                l_[e] += p;
            }
        // P -> fp16, transpose via wave-private LDS (C-layout -> A-frag layout)
#pragma unroll
        for (int ct2 = 0; ct2 < 4; ++ct2)
#pragma unroll
            for (int e = 0; e < 4; ++e) {
                int c = 16 * ct2 + l15;
                int row = 4 * q4 + e;
                pw[((c >> 5) * 64 + ((c >> 3) & 3) * 16 + row) * 8 + (c & 7)] = (_Float16)s[ct2][e];
            }
        h8 pf0 = *(h8*)(pw + (0 * 64 + lane) * 8);
        h8 pf1 = *(h8*)(pw + (1 * 64 + lane) * 8);

        // ---- O += P @ Hd ----
#pragma unroll
        for (int ct = 0; ct < 16; ++ct) {
            h8 hf0 = *(const h8*)(hd_pack + (size_t)((ct * 64 + itc * 2 + 0) * 64 + lane) * 8);
            h8 hf1 = *(const h8*)(hd_pack + (size_t)((ct * 64 + itc * 2 + 1) * 64 + lane) * 8);
            __builtin_amdgcn_s_setprio(1);
            o[ct] = MFMA16(pf0, hf0, o[ct]);
            o[ct] = MFMA16(pf1, hf1, o[ct]);
            __builtin_amdgcn_s_setprio(0);
        }
    }

    // ---- final: reduce l over the 16 lanes of each row, normalize, store ----
#pragma unroll
    for (int off = 1; off < 16; off <<= 1)
#pragma unroll
        for (int e = 0; e < 4; ++e)
            l_[e] += __shfl_xor(l_[e], off, 64);
    float inv[4];
#pragma unroll
    for (int e = 0; e < 4; ++e) inv[e] = 1.f / l_[e];

#pragma unroll
    for (int ct = 0; ct < 16; ++ct)
#pragma unroll
        for (int e = 0; e < 4; ++e) {
            int row = w * 16 + 4 * q4 + e;
            out[((size_t)blk * 128 + row) * 256 + 16 * ct + l15] = o[ct][e] * inv[e];
        }
}

extern "C" void kernel_launch(void* const* d_in, const int* in_sizes, int n_in,
                              void* d_out, int out_size, void* d_ws, size_t ws_size,
                              hipStream_t stream)
{
    const float* Hr = (const float*)d_in[0];
    const float* Hd = (const float*)d_in[1];
    const float* U  = (const float*)d_in[2];
    const float* V  = (const float*)d_in[3];
    const float* q  = (const float*)d_in[4];
    const float* gr = (const float*)d_in[5];
    const float* br = (const float*)d_in[6];
    const float* gd = (const float*)d_in[7];
    const float* bd = (const float*)d_in[8];
    float* out = (float*)d_out;

    const int N = in_sizes[0] / 256;   // 65536
    const int M = in_sizes[1] / 256;   // 2048

    char* ws = (char*)d_ws;
    _Float16* dp_pack = (_Float16*)ws;                               // 2 MB
    _Float16* hd_pack = (_Float16*)(ws + (2u << 20));                // 1 MB
    _Float16* u_hi    = (_Float16*)(ws + (3u << 20));                // 256 KB
    _Float16* u_lo    = (_Float16*)(ws + (3u << 20) + (256u << 10)); // 256 KB

    dp_kernel<<<dim3(M / 4), dim3(512), 0, stream>>>(V, Hd, gd, bd, dp_pack);
    pack_hd_kernel<<<dim3(M), dim3(256), 0, stream>>>(Hd, hd_pack);
    pack_u_kernel<<<dim3(256), dim3(512), 0, stream>>>(U, u_hi, u_lo);
    attn_kernel<<<dim3(N / 128), dim3(512), 0, stream>>>(Hr, q, gr, br, u_hi, u_lo,
                                                         dp_pack, hd_pack, out);
}

// Round 8
// 866.869 us; speedup vs baseline: 1.0435x; 1.0435x over previous
//
#include <hip/hip_runtime.h>
#include <math.h>

#define LN_EPS 1e-5f

typedef _Float16 h8 __attribute__((ext_vector_type(8)));
typedef _Float16 h4 __attribute__((ext_vector_type(4)));
typedef float f32x4 __attribute__((ext_vector_type(4)));

#define MFMA16(A,B,C) __builtin_amdgcn_mfma_f32_16x16x32_f16(A,B,C,0,0,0)

__device__ __forceinline__ float fast_tanh(float x){
    float e = __expf(2.f*x);
    return 1.f - 2.f/(e+1.f);
}

// ---------------------------------------------------------------------------
// dp_kernel: dp[m][k] = LN_k(tanh(V@Hd^T))*g_d+b_d, fp16, fragment-packed:
//   slot[mt][kk][lane][j] = dp[16*mt + (lane&15)][32*kk + 8*(lane>>4) + j]
// ---------------------------------------------------------------------------
__global__ __launch_bounds__(512) void dp_kernel(
    const float* __restrict__ V, const float* __restrict__ Hd,
    const float* __restrict__ gd, const float* __restrict__ bd,
    _Float16* __restrict__ dp_pack)
{
    __shared__ float h_sh[4][256];
    __shared__ float red1[4][8];
    __shared__ float red2[4][8];

    const int t  = threadIdx.x;
    const int m0 = blockIdx.x * 4;

    for (int i = t; i < 4 * 256; i += 512)
        ((float*)h_sh)[i] = Hd[(size_t)m0 * 256 + i];
    __syncthreads();

    const int k = t;
    float x0 = 0.f, x1 = 0.f, x2 = 0.f, x3 = 0.f;
    for (int j = 0; j < 256; j += 4) {
        float4 v4 = *(const float4*)(V + (size_t)k * 256 + j);
        x0 += v4.x * h_sh[0][j] + v4.y * h_sh[0][j + 1] + v4.z * h_sh[0][j + 2] + v4.w * h_sh[0][j + 3];
        x1 += v4.x * h_sh[1][j] + v4.y * h_sh[1][j + 1] + v4.z * h_sh[1][j + 2] + v4.w * h_sh[1][j + 3];
        x2 += v4.x * h_sh[2][j] + v4.y * h_sh[2][j + 1] + v4.z * h_sh[2][j + 2] + v4.w * h_sh[2][j + 3];
        x3 += v4.x * h_sh[3][j] + v4.y * h_sh[3][j + 1] + v4.z * h_sh[3][j + 2] + v4.w * h_sh[3][j + 3];
    }
    float th[4];
    th[0] = tanhf(x0); th[1] = tanhf(x1); th[2] = tanhf(x2); th[3] = tanhf(x3);

    float s1[4], s2[4];
#pragma unroll
    for (int mi = 0; mi < 4; ++mi) { s1[mi] = th[mi]; s2[mi] = th[mi] * th[mi]; }
#pragma unroll
    for (int off = 32; off > 0; off >>= 1) {
#pragma unroll
        for (int mi = 0; mi < 4; ++mi) {
            s1[mi] += __shfl_xor(s1[mi], off, 64);
            s2[mi] += __shfl_xor(s2[mi], off, 64);
        }
    }
    const int wave = t >> 6;
    if ((t & 63) == 0) {
#pragma unroll
        for (int mi = 0; mi < 4; ++mi) { red1[mi][wave] = s1[mi]; red2[mi][wave] = s2[mi]; }
    }
    __syncthreads();

    const float gk = gd[k];
    const float bk = bd[k];
#pragma unroll
    for (int mi = 0; mi < 4; ++mi) {
        float sa = 0.f, sb = 0.f;
#pragma unroll
        for (int ww = 0; ww < 8; ++ww) { sa += red1[mi][ww]; sb += red2[mi][ww]; }
        float mu  = sa * (1.f / 512.f);
        float var = sb * (1.f / 512.f) - mu * mu;
        float rs  = rsqrtf(var + LN_EPS);
        float a   = (th[mi] - mu) * rs * gk + bk;
        int m  = m0 + mi;
        int mt = m >> 4, kk = k >> 5, ln = (m & 15) + 16 * ((k >> 3) & 3), j = k & 7;
        dp_pack[(size_t)((mt * 16 + kk) * 64 + ln) * 8 + j] = (_Float16)a;
    }
}

// hd_pack[nt][kk][lane][j] = Hd[32*kk + 8*(lane>>4)+j][16*nt + (lane&15)]  (fp16)
__global__ void pack_hd_kernel(const float* __restrict__ Hd, _Float16* __restrict__ hp)
{
    int m = blockIdx.x, c = threadIdx.x;
    float v = Hd[(size_t)m * 256 + c];
    int nt = c >> 4, kk = m >> 5, ln = (c & 15) + 16 * ((m >> 3) & 3), j = m & 7;
    hp[(size_t)((nt * 64 + kk) * 64 + ln) * 8 + j] = (_Float16)v;
}

// u_pack[nt][kd][lane][jj] = U[32*kd + 8*(lane>>4)+jj][16*nt + (lane&15)]  hi/lo fp16
__global__ void pack_u_kernel(const float* __restrict__ U,
                              _Float16* __restrict__ uh, _Float16* __restrict__ ul)
{
    int jd = blockIdx.x, n = threadIdx.x;
    float v = U[(size_t)jd * 512 + n];
    _Float16 hi = (_Float16)v;
    _Float16 lo = (_Float16)(v - (float)hi);
    int nt = n >> 4, kd = jd >> 5, ln = (n & 15) + 16 * ((jd >> 3) & 3), jj = jd & 7;
    int idx = ((nt * 8 + kd) * 64 + ln) * 8 + jj;
    uh[idx] = hi; ul[idx] = lo;
}

// ---------------------------------------------------------------------------
// Main kernel: 128 rows/block, 512 threads (8 waves), WAVE-DECOUPLED M-loop.
// REGISTER MODEL (from rounds 1/5/6/7): gfx950 unified VGPR/AGPR file;
// 512-thread block -> 2 waves/SIMD floor -> 256 unified = 128 arch-VGPR +
// 128 AGPR, and rocprof VGPR_Count shows only the 128 arch half. Rounds 5-7
// spilled ~10 VGPRs/iter (WRITE ~266MB) because the VGPR side held a[16]
// (64 regs) + staging + softmax > 128. FIX: drop the register-held a tile,
// read the A-fragment from a_pack (LDS) per kk -- one conflict-free
// ds_read_b128, round-4-style. VGPR side ~75 -> no spill. AGPR side keeps
// o[16] + MFMA accumulators. M-loop still has zero barriers.
// ---------------------------------------------------------------------------
__global__ __launch_bounds__(512, 1) void attn_kernel(
    const float* __restrict__ Hr, const float* __restrict__ q,
    const float* __restrict__ gr, const float* __restrict__ br,
    const _Float16* __restrict__ u_hi, const _Float16* __restrict__ u_lo,
    const _Float16* __restrict__ dp_pack, const _Float16* __restrict__ hd_pack,
    float* __restrict__ out)
{
    __shared__ __align__(16) _Float16 lds0[65536];   // 128 KB: hr staging / a_pack
    __shared__ __align__(16) _Float16 p_lds[8192];   // 16 KB: per-wave P transpose
    __shared__ __align__(16) float stats[2][64][8];  // 4 KB: phase-A LN stats

    const int t    = threadIdx.x;
    const int w    = t >> 6;       // 0..7
    const int lane = t & 63;
    const int q4   = lane >> 4;
    const int l15  = lane & 15;
    const int blk  = blockIdx.x;

    _Float16* hr_hi  = lds0 + 32768;   // bytes [64K,96K)
    _Float16* hr_lo  = lds0 + 49152;   // bytes [96K,128K)
    _Float16* a_pack = lds0;           // rt'=0..7 -> [0,128K)

    // per-thread LN gate params for this wave's 64 K-cols
    float gq[4], bq[4];
#pragma unroll
    for (int i = 0; i < 4; ++i) {
        int c = w * 64 + 16 * i + l15;
        gq[i] = gr[c] * q[c];
        bq[i] = br[c] * q[c];
    }

    // ======================= phase A: two 64-row passes =======================
    for (int pass = 0; pass < 2; ++pass) {
        // stage 64 rows of Hr -> hi/lo A-fragments (coalesced, NT loads)
        const float* HrB = Hr + ((size_t)blk * 128 + pass * 64) * 256;
#pragma unroll
        for (int ii = 0; ii < 8; ++ii) {
            int flat = (t + 512 * ii) * 4;
            int r = flat >> 8, c = flat & 255;
            f32x4 v = __builtin_nontemporal_load((const f32x4*)(HrB + flat));
            int base = (((r >> 4) * 8 + (c >> 5)) * 64 + ((r & 15) + 16 * ((c >> 3) & 3))) * 8 + (c & 7);
            h4 hi, lo;
            hi[0] = (_Float16)v[0]; lo[0] = (_Float16)(v[0] - (float)hi[0]);
            hi[1] = (_Float16)v[1]; lo[1] = (_Float16)(v[1] - (float)hi[1]);
            hi[2] = (_Float16)v[2]; lo[2] = (_Float16)(v[2] - (float)hi[2]);
            hi[3] = (_Float16)v[3]; lo[3] = (_Float16)(v[3] - (float)hi[3]);
            *(h4*)(hr_hi + base) = hi;
            *(h4*)(hr_lo + base) = lo;
        }
        __syncthreads();   // staging complete

        // x[rt][ci] = Hr@U (split fp16 3-product); wave owns K-cols [w*64, +64)
        f32x4 x[4][4];
#pragma unroll
        for (int rt = 0; rt < 4; ++rt)
#pragma unroll
            for (int ci = 0; ci < 4; ++ci) x[rt][ci] = (f32x4)(0.f);

#pragma unroll
        for (int kd = 0; kd < 8; ++kd) {
            h8 ah[4], al[4];
#pragma unroll
            for (int rt = 0; rt < 4; ++rt) {
                int idx = ((rt * 8 + kd) * 64 + lane) * 8;
                ah[rt] = *(h8*)(hr_hi + idx);
                al[rt] = *(h8*)(hr_lo + idx);
            }
            h8 bh[4], bl[4];
#pragma unroll
            for (int ci = 0; ci < 4; ++ci) {
                int idx = (((w * 4 + ci) * 8 + kd) * 64 + lane) * 8;
                bh[ci] = *(const h8*)(u_hi + idx);
                bl[ci] = *(const h8*)(u_lo + idx);
            }
            __builtin_amdgcn_s_setprio(1);
#pragma unroll
            for (int rt = 0; rt < 4; ++rt)
#pragma unroll
                for (int ci = 0; ci < 4; ++ci) x[rt][ci] = MFMA16(ah[rt], bh[ci], x[rt][ci]);
#pragma unroll
            for (int rt = 0; rt < 4; ++rt)
#pragma unroll
                for (int ci = 0; ci < 4; ++ci) x[rt][ci] = MFMA16(ah[rt], bl[ci], x[rt][ci]);
#pragma unroll
            for (int rt = 0; rt < 4; ++rt)
#pragma unroll
                for (int ci = 0; ci < 4; ++ci) x[rt][ci] = MFMA16(al[rt], bh[ci], x[rt][ci]);
            __builtin_amdgcn_s_setprio(0);
        }

        // tanh + LN stats (8-wave reduction through LDS)
        float s1[4][4], s2[4][4];
#pragma unroll
        for (int rt = 0; rt < 4; ++rt)
#pragma unroll
            for (int e = 0; e < 4; ++e) { s1[rt][e] = 0.f; s2[rt][e] = 0.f; }
#pragma unroll
        for (int rt = 0; rt < 4; ++rt)
#pragma unroll
            for (int ci = 0; ci < 4; ++ci)
#pragma unroll
                for (int e = 0; e < 4; ++e) {
                    float th = fast_tanh(x[rt][ci][e]);
                    x[rt][ci][e] = th;
                    s1[rt][e] += th;
                    s2[rt][e] += th * th;
                }
#pragma unroll
        for (int off = 1; off < 16; off <<= 1)
#pragma unroll
            for (int rt = 0; rt < 4; ++rt)
#pragma unroll
                for (int e = 0; e < 4; ++e) {
                    s1[rt][e] += __shfl_xor(s1[rt][e], off, 64);
                    s2[rt][e] += __shfl_xor(s2[rt][e], off, 64);
                }
        if (l15 == 0) {
#pragma unroll
            for (int rt = 0; rt < 4; ++rt)
#pragma unroll
                for (int e = 0; e < 4; ++e) {
                    int row = rt * 16 + q4 * 4 + e;
                    stats[0][row][w] = s1[rt][e];
                    stats[1][row][w] = s2[rt][e];
                }
        }
        __syncthreads();   // stats visible (also fences hr reads before reuse)

        float mu[4][4], rs_[4][4];
#pragma unroll
        for (int rt = 0; rt < 4; ++rt)
#pragma unroll
            for (int e = 0; e < 4; ++e) {
                int row = rt * 16 + q4 * 4 + e;
                f32x4 v1  = *(f32x4*)&stats[0][row][0];
                f32x4 v1b = *(f32x4*)&stats[0][row][4];
                f32x4 v2  = *(f32x4*)&stats[1][row][0];
                f32x4 v2b = *(f32x4*)&stats[1][row][4];
                float S1 = v1[0]+v1[1]+v1[2]+v1[3]+v1b[0]+v1b[1]+v1b[2]+v1b[3];
                float S2 = v2[0]+v2[1]+v2[2]+v2[3]+v2b[0]+v2b[1]+v2b[2]+v2b[3];
                float m  = S1 * (1.f / 512.f);
                float va = S2 * (1.f / 512.f) - m * m;
                mu[rt][e]  = m;
                rs_[rt][e] = rsqrtf(va + LN_EPS);
            }

        // LN affine + gate -> a_pack (pass 0 -> [0,64K) bytes; pass 1 overwrites hr)
#pragma unroll
        for (int rt = 0; rt < 4; ++rt)
#pragma unroll
            for (int ci = 0; ci < 4; ++ci)
#pragma unroll
                for (int e = 0; e < 4; ++e) {
                    int mrow = q4 * 4 + e;
                    int c = w * 64 + 16 * ci + l15;
                    float a = (x[rt][ci][e] - mu[rt][e]) * rs_[rt][e] * gq[ci] + bq[ci];
                    a_pack[(((pass * 4 + rt) * 16 + (c >> 5)) * 64 + (mrow + 16 * ((c >> 3) & 3))) * 8 + (c & 7)] =
                        (_Float16)a;
                }
    }
    __syncthreads();   // a_pack complete (written by all waves)

    // ======================= wave-decoupled flash M-loop ======================
    // A-fragments stay in LDS (a_pack); one ds_read_b128 per kk per rt-slot.
    // This keeps the arch-VGPR side under 128 (no scratch spill).
    const _Float16* aw = a_pack + (w * 16 * 64) * 8;   // this wave's 16-row tile
    _Float16* pw = p_lds + w * 1024;                   // wave-private 2 KB

    f32x4 o[16];
#pragma unroll
    for (int ct = 0; ct < 16; ++ct) o[ct] = (f32x4)(0.f);
    float m_[4], l_[4];
#pragma unroll
    for (int e = 0; e < 4; ++e) { m_[e] = -3.0e38f; l_[e] = 0.f; }

    for (int itc = 0; itc < 32; ++itc) {   // chunk = 64 M-cols
        // ---- S = a @ dp^T ----
        f32x4 s[4];
#pragma unroll
        for (int ct2 = 0; ct2 < 4; ++ct2) s[ct2] = (f32x4)(0.f);

        __builtin_amdgcn_s_setprio(1);
#pragma unroll
        for (int kk = 0; kk < 16; ++kk) {
            h8 af = *(const h8*)(aw + (kk * 64 + lane) * 8);
            h8 bf[4];
#pragma unroll
            for (int ct2 = 0; ct2 < 4; ++ct2)
                bf[ct2] = *(const h8*)(dp_pack + (size_t)(((itc * 4 + ct2) * 16 + kk) * 64 + lane) * 8);
#pragma unroll
            for (int ct2 = 0; ct2 < 4; ++ct2)
                s[ct2] = MFMA16(af, bf[ct2], s[ct2]);
        }
        __builtin_amdgcn_s_setprio(0);

        // ---- wave-local online softmax over this chunk ----
        float pm[4];
#pragma unroll
        for (int e = 0; e < 4; ++e)
            pm[e] = fmaxf(fmaxf(s[0][e], s[1][e]), fmaxf(s[2][e], s[3][e]));
#pragma unroll
        for (int off = 1; off < 16; off <<= 1)
#pragma unroll
            for (int e = 0; e < 4; ++e)
                pm[e] = fmaxf(pm[e], __shfl_xor(pm[e], off, 64));

        float grow = fmaxf(fmaxf(pm[0] - m_[0], pm[1] - m_[1]),
                           fmaxf(pm[2] - m_[2], pm[3] - m_[3]));
        if (__any(grow > 8.f)) {   // T13 defer-max: rescale only on real growth
#pragma unroll
            for (int e = 0; e < 4; ++e) {
                float mn = fmaxf(m_[e], pm[e]);
                float al = __expf(m_[e] - mn);
                m_[e] = mn;
                l_[e] *= al;
#pragma unroll
                for (int ct = 0; ct < 16; ++ct) o[ct][e] *= al;
            }
        }
        // P = exp(S - m); l as per-thread partial (no cross-lane reduce here)
#pragma unroll
        for (int ct2 = 0; ct2 < 4; ++ct2)
#pragma unroll
            for (int e = 0; e < 4; ++e) {
                float p = __expf(s[ct2][e] - m_[e]);
                s[ct2][e] = p;
                l_[e] += p;
            }
        // P -> fp16, transpose via wave-private LDS (C-layout -> A-frag layout)
#pragma unroll
        for (int ct2 = 0; ct2 < 4; ++ct2)
#pragma unroll
            for (int e = 0; e < 4; ++e) {
                int c = 16 * ct2 + l15;
                int row = 4 * q4 + e;
                pw[((c >> 5) * 64 + ((c >> 3) & 3) * 16 + row) * 8 + (c & 7)] = (_Float16)s[ct2][e];
            }
        h8 pf0 = *(h8*)(pw + (0 * 64 + lane) * 8);
        h8 pf1 = *(h8*)(pw + (1 * 64 + lane) * 8);

        // ---- O += P @ Hd ----
        __builtin_amdgcn_s_setprio(1);
#pragma unroll
        for (int ct = 0; ct < 16; ++ct) {
            h8 hf0 = *(const h8*)(hd_pack + (size_t)((ct * 64 + itc * 2 + 0) * 64 + lane) * 8);
            h8 hf1 = *(const h8*)(hd_pack + (size_t)((ct * 64 + itc * 2 + 1) * 64 + lane) * 8);
            o[ct] = MFMA16(pf0, hf0, o[ct]);
            o[ct] = MFMA16(pf1, hf1, o[ct]);
        }
        __builtin_amdgcn_s_setprio(0);
    }

    // ---- final: reduce l over the 16 lanes of each row, normalize, store ----
#pragma unroll
    for (int off = 1; off < 16; off <<= 1)
#pragma unroll
        for (int e = 0; e < 4; ++e)
            l_[e] += __shfl_xor(l_[e], off, 64);
    float inv[4];
#pragma unroll
    for (int e = 0; e < 4; ++e) inv[e] = 1.f / l_[e];

#pragma unroll
    for (int ct = 0; ct < 16; ++ct)
#pragma unroll
        for (int e = 0; e < 4; ++e) {
            int row = w * 16 + 4 * q4 + e;
            out[((size_t)blk * 128 + row) * 256 + 16 * ct + l15] = o[ct][e] * inv[e];
        }
}

extern "C" void kernel_launch(void* const* d_in, const int* in_sizes, int n_in,
                              void* d_out, int out_size, void* d_ws, size_t ws_size,
                              hipStream_t stream)
{
    const float* Hr = (const float*)d_in[0];
    const float* Hd = (const float*)d_in[1];
    const float* U  = (const float*)d_in[2];
    const float* V  = (const float*)d_in[3];
    const float* q  = (const float*)d_in[4];
    const float* gr = (const float*)d_in[5];
    const float* br = (const float*)d_in[6];
    const float* gd = (const float*)d_in[7];
    const float* bd = (const float*)d_in[8];
    float* out = (float*)d_out;

    const int N = in_sizes[0] / 256;   // 65536
    const int M = in_sizes[1] / 256;   // 2048

    char* ws = (char*)d_ws;
    _Float16* dp_pack = (_Float16*)ws;                               // 2 MB
    _Float16* hd_pack = (_Float16*)(ws + (2u << 20));                // 1 MB
    _Float16* u_hi    = (_Float16*)(ws + (3u << 20));                // 256 KB
    _Float16* u_lo    = (_Float16*)(ws + (3u << 20) + (256u << 10)); // 256 KB

    dp_kernel<<<dim3(M / 4), dim3(512), 0, stream>>>(V, Hd, gd, bd, dp_pack);
    pack_hd_kernel<<<dim3(M), dim3(256), 0, stream>>>(Hd, hd_pack);
    pack_u_kernel<<<dim3(256), dim3(512), 0, stream>>>(U, u_hi, u_lo);
    attn_kernel<<<dim3(N / 128), dim3(512), 0, stream>>>(Hr, q, gr, br, u_hi, u_lo,
                                                         dp_pack, hd_pack, out);
}